// Round 1
// baseline (174.625 us; speedup 1.0000x reference)
//
#include <hip/hip_runtime.h>

// out[b][j] = x[b][(j - s_b) mod T]
// Vectorized: each thread produces 4 consecutive output elements (float4 store),
// reading 4 contiguous (possibly wrapping) source elements with scalar loads.
__global__ void roll_rows_vec4(const float* __restrict__ x,
                               const int* __restrict__ shifts,
                               float* __restrict__ out,
                               int T, int T4) {
    const int b = blockIdx.y;
    const int v = blockIdx.x * blockDim.x + threadIdx.x;
    if (v >= T4) return;

    // shifts are in [0, 1000) per the reference; normalize defensively.
    int s = shifts[b] % T;
    if (s < 0) s += T;

    const int j = v * 4;
    int i0 = j - s;
    if (i0 < 0) i0 += T;

    const float* __restrict__ xr = x + (size_t)b * (size_t)T;
    float4 r;
    if (i0 + 3 < T) {
        // common path: contiguous, no wrap
        r.x = xr[i0];
        r.y = xr[i0 + 1];
        r.z = xr[i0 + 2];
        r.w = xr[i0 + 3];
    } else {
        int i1 = i0 + 1; if (i1 >= T) i1 -= T;
        int i2 = i0 + 2; if (i2 >= T) i2 -= T;
        int i3 = i0 + 3; if (i3 >= T) i3 -= T;
        r.x = xr[i0];
        r.y = xr[i1];
        r.z = xr[i2];
        r.w = xr[i3];
    }
    *reinterpret_cast<float4*>(out + (size_t)b * (size_t)T + j) = r;
}

// Generic scalar fallback (T not divisible by 4).
__global__ void roll_rows_scalar(const float* __restrict__ x,
                                 const int* __restrict__ shifts,
                                 float* __restrict__ out,
                                 int T) {
    const int b = blockIdx.y;
    const int j = blockIdx.x * blockDim.x + threadIdx.x;
    if (j >= T) return;
    int s = shifts[b] % T;
    if (s < 0) s += T;
    int i = j - s;
    if (i < 0) i += T;
    out[(size_t)b * T + j] = x[(size_t)b * T + i];
}

extern "C" void kernel_launch(void* const* d_in, const int* in_sizes, int n_in,
                              void* d_out, int out_size, void* d_ws, size_t ws_size,
                              hipStream_t stream) {
    const float* x = (const float*)d_in[0];
    const int* shifts = (const int*)d_in[1];
    float* out = (float*)d_out;

    const int B = in_sizes[1];
    const int T = in_sizes[0] / B;

    if ((T & 3) == 0) {
        const int T4 = T / 4;
        dim3 block(256);
        dim3 grid((T4 + 255) / 256, B);
        roll_rows_vec4<<<grid, block, 0, stream>>>(x, shifts, out, T, T4);
    } else {
        dim3 block(256);
        dim3 grid((T + 255) / 256, B);
        roll_rows_scalar<<<grid, block, 0, stream>>>(x, shifts, out, T);
    }
}